// Round 2
// baseline (527.663 us; speedup 1.0000x reference)
//
#include <hip/hip_runtime.h>

// Problem constants (match reference setup_inputs)
#define FF 8
#define BB 4096
#define VV 100000
#define DD 128
#define NN 81920

// One wave (64 lanes) per (feature, bag). The wave is split into two
// 32-lane halves; each half owns one table row per step, lane reads float4
// (32 lanes x 16B = 512B = one full D=128 row per half). So each loop step
// processes 2 rows, unrolled x2 -> 4 rows (2KB) in flight per wave.
// Epilogue combines the two halves with __shfl_xor(.,32).
__global__ __launch_bounds__(256, 8) void ebc_pool_kernel(
    const int* __restrict__ values,   // [F, N]
    const int* __restrict__ offsets,  // [F, B+1]
    const float* __restrict__ tables, // [F, V, D]
    float* __restrict__ out)          // [B, F*D]
{
    const int wave = threadIdx.x >> 6;             // 0..3
    const int lane = threadIdx.x & 63;
    const int half = lane >> 5;                    // 0 or 1
    const int hl   = lane & 31;                    // lane within half
    const int gbag = blockIdx.x * 4 + wave;        // 0 .. F*B-1
    const int f = gbag >> 12;                      // / BB
    const int b = gbag & (BB - 1);

    const int* __restrict__ offs = offsets + f * (BB + 1);
    const int start = offs[b];
    const int end   = offs[b + 1];

    const int* __restrict__ vals = values + f * NN;
    const float* __restrict__ tab = tables + (size_t)f * VV * DD;

    float4 acc = make_float4(0.f, 0.f, 0.f, 0.f);

    int i = start;
    // main loop: 4 rows per iteration (2 per half), 2KB in flight
    for (; i + 4 <= end; i += 4) {
        const int i0 = vals[i + 0];
        const int i1 = vals[i + 1];
        const int i2 = vals[i + 2];
        const int i3 = vals[i + 3];
        const int r0 = half ? i1 : i0;
        const int r1 = half ? i3 : i2;
        const float4 v0 = ((const float4*)(tab + (size_t)r0 * DD))[hl];
        const float4 v1 = ((const float4*)(tab + (size_t)r1 * DD))[hl];
        acc.x += v0.x + v1.x;
        acc.y += v0.y + v1.y;
        acc.z += v0.z + v1.z;
        acc.w += v0.w + v1.w;
    }
    // tail: 2 rows per iteration, predicated
    for (; i < end; i += 2) {
        const int ii = i + half;
        if (ii < end) {
            const int r = vals[ii];
            const float4 v = ((const float4*)(tab + (size_t)r * DD))[hl];
            acc.x += v.x;
            acc.y += v.y;
            acc.z += v.z;
            acc.w += v.w;
        }
    }

    // combine the two 32-lane halves (each lane pair (hl, hl+32) owns the
    // same 4 dims)
    acc.x += __shfl_xor(acc.x, 32, 64);
    acc.y += __shfl_xor(acc.y, 32, 64);
    acc.z += __shfl_xor(acc.z, 32, 64);
    acc.w += __shfl_xor(acc.w, 32, 64);

    if (half == 0) {
        float4* __restrict__ o =
            (float4*)(out + (size_t)b * (FF * DD) + f * DD);
        o[hl] = acc;
    }
}

extern "C" void kernel_launch(void* const* d_in, const int* in_sizes, int n_in,
                              void* d_out, int out_size, void* d_ws, size_t ws_size,
                              hipStream_t stream) {
    const int*   values  = (const int*)d_in[0];    // [F, N] int32
    const int*   offsets = (const int*)d_in[1];    // [F, B+1] int32
    const float* tables  = (const float*)d_in[2];  // [F, V, D] float32
    float*       out     = (float*)d_out;          // [B, F*D] float32

    const int total_bags = FF * BB;                // 32768
    const int blocks = total_bags / 4;             // 8192 blocks of 256 threads
    ebc_pool_kernel<<<blocks, 256, 0, stream>>>(values, offsets, tables, out);
}

// Round 3
// 515.850 us; speedup vs baseline: 1.0229x; 1.0229x over previous
//
#include <hip/hip_runtime.h>

// Problem constants (match reference setup_inputs)
#define FF 8
#define BB 4096
#define VV 100000
#define DD 128
#define NN 81920

// One wave (64 lanes) per (feature, bag). Wave is split into two 32-lane
// halves; each half reads one full D=128 row per float4 load (32 x 16B =
// 512B). Main loop: 8 rows / iteration = 4 independent dwordx4 gathers
// (4KB) in flight per wave. Bag bounds are readfirstlane'd to SGPRs so the
// index stream goes through the scalar cache (s_load) and loop control is
// scalar.
__global__ __launch_bounds__(256, 8) void ebc_pool_kernel(
    const int* __restrict__ values,   // [F, N]
    const int* __restrict__ offsets,  // [F, B+1]
    const float* __restrict__ tables, // [F, V, D]
    float* __restrict__ out)          // [B, F*D]
{
    const int wave = threadIdx.x >> 6;             // 0..3
    const int lane = threadIdx.x & 63;
    const int half = lane >> 5;                    // 0 or 1
    const int hl   = lane & 31;                    // lane within half

    // XCD-aware swizzle: feature = blockIdx % 8, so each XCD's L2 caches
    // (mostly) a single 51MB table's working set instead of all 8.
    const int f   = blockIdx.x & 7;
    const int bb4 = blockIdx.x >> 3;               // 0..1023
    const int b   = bb4 * 4 + wave;                // bag id in [0, BB)

    const int* __restrict__ offs = offsets + f * (BB + 1);
    const int start = __builtin_amdgcn_readfirstlane(offs[b]);
    const int end   = __builtin_amdgcn_readfirstlane(offs[b + 1]);

    const int* __restrict__ vals = values + f * NN;
    const float* __restrict__ tab = tables + (size_t)f * VV * DD;

    float4 acc0 = make_float4(0.f, 0.f, 0.f, 0.f);
    float4 acc1 = make_float4(0.f, 0.f, 0.f, 0.f);

    int i = start;
    // main loop: 8 rows per iteration (4 per half), 4 loads in flight
    for (; i + 8 <= end; i += 8) {
        const int a0 = vals[i + 0];
        const int a1 = vals[i + 1];
        const int a2 = vals[i + 2];
        const int a3 = vals[i + 3];
        const int a4 = vals[i + 4];
        const int a5 = vals[i + 5];
        const int a6 = vals[i + 6];
        const int a7 = vals[i + 7];
        const int r0 = half ? a1 : a0;
        const int r1 = half ? a3 : a2;
        const int r2 = half ? a5 : a4;
        const int r3 = half ? a7 : a6;
        const float4 v0 = ((const float4*)(tab + (size_t)r0 * DD))[hl];
        const float4 v1 = ((const float4*)(tab + (size_t)r1 * DD))[hl];
        const float4 v2 = ((const float4*)(tab + (size_t)r2 * DD))[hl];
        const float4 v3 = ((const float4*)(tab + (size_t)r3 * DD))[hl];
        acc0.x += v0.x + v1.x;
        acc0.y += v0.y + v1.y;
        acc0.z += v0.z + v1.z;
        acc0.w += v0.w + v1.w;
        acc1.x += v2.x + v3.x;
        acc1.y += v2.y + v3.y;
        acc1.z += v2.z + v3.z;
        acc1.w += v2.w + v3.w;
    }
    // tail: 2 rows per iteration, predicated on the last odd element
    for (; i < end; i += 2) {
        const int ii = i + half;
        if (ii < end) {
            const int r = vals[ii];
            const float4 v = ((const float4*)(tab + (size_t)r * DD))[hl];
            acc0.x += v.x;
            acc0.y += v.y;
            acc0.z += v.z;
            acc0.w += v.w;
        }
    }

    acc0.x += acc1.x; acc0.y += acc1.y; acc0.z += acc1.z; acc0.w += acc1.w;

    // combine the two 32-lane halves (lane pair (hl, hl+32) owns same dims)
    acc0.x += __shfl_xor(acc0.x, 32, 64);
    acc0.y += __shfl_xor(acc0.y, 32, 64);
    acc0.z += __shfl_xor(acc0.z, 32, 64);
    acc0.w += __shfl_xor(acc0.w, 32, 64);

    if (half == 0) {
        float4* __restrict__ o =
            (float4*)(out + (size_t)b * (FF * DD) + f * DD);
        o[hl] = acc0;
    }
}

extern "C" void kernel_launch(void* const* d_in, const int* in_sizes, int n_in,
                              void* d_out, int out_size, void* d_ws, size_t ws_size,
                              hipStream_t stream) {
    const int*   values  = (const int*)d_in[0];    // [F, N] int32
    const int*   offsets = (const int*)d_in[1];    // [F, B+1] int32
    const float* tables  = (const float*)d_in[2];  // [F, V, D] float32
    float*       out     = (float*)d_out;          // [B, F*D] float32

    const int total_bags = FF * BB;                // 32768
    const int blocks = total_bags / 4;             // 8192 blocks of 256 threads
    ebc_pool_kernel<<<blocks, 256, 0, stream>>>(values, offsets, tables, out);
}